// Round 2
// baseline (268.595 us; speedup 1.0000x reference)
//
#include <hip/hip_runtime.h>
#include <stdint.h>

#define DEV static __device__ __forceinline__

typedef __attribute__((ext_vector_type(8))) __bf16 bfx8;
typedef __attribute__((ext_vector_type(4))) float f32x4;

DEV short f2bfbits(float f) {
  union { float f; unsigned u; } v; v.f = f;
  unsigned r = v.u + 0x7fffu + ((v.u >> 16) & 1u);
  return (short)(r >> 16);
}

DEV void gload_lds16(const void* g, void* lds) {
  __builtin_amdgcn_global_load_lds(
      (const __attribute__((address_space(1))) void*)g,
      (__attribute__((address_space(3))) void*)lds, 16, 0, 0);
}

// ---------------- prep kernels ----------------

__global__ void k_cvt_x(const float* __restrict__ src, short* __restrict__ dst) {
  int i = blockIdx.x * 256 + threadIdx.x;            // 4 floats per thread
  float4 v = ((const float4*)src)[i];
  union { short s[4]; uint64_t u; } o;
  o.s[0] = f2bfbits(v.x); o.s[1] = f2bfbits(v.y);
  o.s[2] = f2bfbits(v.z); o.s[3] = f2bfbits(v.w);
  ((uint64_t*)dst)[i] = o.u;
}

// src [R][C] f32 -> dst [C][R] bf16
__global__ void k_transpose(const float* __restrict__ src, short* __restrict__ dst,
                            int R, int C) {
  __shared__ float tile[32][33];
  int c0 = blockIdx.x * 32, r0 = blockIdx.y * 32;
  int tx = threadIdx.x, ty = threadIdx.y;            // block (32,8)
  #pragma unroll
  for (int j = 0; j < 32; j += 8)
    tile[ty + j][tx] = src[(size_t)(r0 + ty + j) * C + c0 + tx];
  __syncthreads();
  #pragma unroll
  for (int j = 0; j < 32; j += 8)
    dst[(size_t)(c0 + ty + j) * R + r0 + tx] = f2bfbits(tile[tx][ty + j]);
}

// msk[b][n]: n==0 -> 1 else mask[b][n-1]
__global__ void k_mask(const int* __restrict__ mask, unsigned char* __restrict__ msk) {
  int i = blockIdx.x * 256 + threadIdx.x;            // [0, 4096)
  int b = i >> 10, n = i & 1023;
  msk[i] = (n == 0) ? (unsigned char)1 : (unsigned char)(mask[b * 1023 + n - 1] != 0);
}

// ---------------- GEMM: C = A[M][K] @ Bt[N][K]^T + bias ----------------
// mode 0: scatter to q/k/vT (bf16), N=3072.  mode 1: f32 out + bias, N=1024.
__global__ __launch_bounds__(256)
void k_gemm(const short* __restrict__ A, const short* __restrict__ Bt,
            const float* __restrict__ bias, int K, int mode,
            short* __restrict__ q, short* __restrict__ kk,
            short* __restrict__ vT, float* __restrict__ outF) {
  __shared__ short As[128 * 32];
  __shared__ short Bs[128 * 32];
  const int t = threadIdx.x;
  const int l = t & 63, w = t >> 6;
  const int lr = l & 15, lk = l >> 4;
  const int m0 = blockIdx.y * 128, n0 = blockIdx.x * 128;
  const int wr = (w >> 1) * 64, wc = (w & 1) * 64;
  f32x4 acc[4][4] = {};

  const int srow = t >> 2;
  const int sc8 = (t & 3) * 8;
  const size_t aoff1 = (size_t)(m0 + srow) * K + sc8;
  const size_t aoff2 = (size_t)(m0 + srow + 64) * K + sc8;
  const size_t boff1 = (size_t)(n0 + srow) * K + sc8;
  const size_t boff2 = (size_t)(n0 + srow + 64) * K + sc8;
  short* asd1 = As + (t & ~63) * 8;
  short* asd2 = As + (t & ~63) * 8 + 2048;
  short* bsd1 = Bs + (t & ~63) * 8;
  short* bsd2 = Bs + (t & ~63) * 8 + 2048;

  for (int k0 = 0; k0 < K; k0 += 32) {
    gload_lds16(A + aoff1 + k0, asd1);
    gload_lds16(A + aoff2 + k0, asd2);
    gload_lds16(Bt + boff1 + k0, bsd1);
    gload_lds16(Bt + boff2 + k0, bsd2);
    __syncthreads();
    bfx8 af[4], bf[4];
    #pragma unroll
    for (int m = 0; m < 4; m++)
      af[m] = *(const bfx8*)&As[(wr + m * 16 + lr) * 32 + lk * 8];
    #pragma unroll
    for (int n = 0; n < 4; n++)
      bf[n] = *(const bfx8*)&Bs[(wc + n * 16 + lr) * 32 + lk * 8];
    #pragma unroll
    for (int m = 0; m < 4; m++)
      #pragma unroll
      for (int n = 0; n < 4; n++)
        acc[m][n] = __builtin_amdgcn_mfma_f32_16x16x32_bf16(af[m], bf[n], acc[m][n], 0, 0, 0);
    __syncthreads();
  }

  if (mode == 0) {
    #pragma unroll
    for (int m = 0; m < 4; m++) {
      int grb = m0 + wr + m * 16 + 4 * lk;
      #pragma unroll
      for (int n = 0; n < 4; n++) {
        int gc = n0 + wc + n * 16 + lr;
        float bv = bias[gc];
        int which = gc >> 10, rem = gc & 1023;
        int hh = rem >> 6, dd = rem & 63;
        #pragma unroll
        for (int i = 0; i < 4; i++) {
          int gr = grb + i;
          int bb = gr >> 10, nn = gr & 1023;
          size_t bh = (size_t)(bb * 16 + hh);
          short val = f2bfbits(acc[m][n][i] + bv);
          if (which == 0)      q [(bh << 16) + ((size_t)nn << 6) + dd] = val;
          else if (which == 1) kk[(bh << 16) + ((size_t)nn << 6) + dd] = val;
          else                 vT[(bh << 16) + ((size_t)dd << 10) + nn] = val;
        }
      }
    }
  } else {
    #pragma unroll
    for (int m = 0; m < 4; m++) {
      #pragma unroll
      for (int n = 0; n < 4; n++) {
        int gc = n0 + wc + n * 16 + lr;
        float bv = bias[gc];
        #pragma unroll
        for (int i = 0; i < 4; i++) {
          int gr = m0 + wr + m * 16 + 4 * lk + i;
          outF[(size_t)gr * 1024 + gc] = acc[m][n][i] + bv;
        }
      }
    }
  }
}

// ---------------- fused attention ----------------
// One workgroup = one (b,h) x 16 query rows, 4 waves.
// Swapped QK^T: mfma(K_frag, Q_frag) -> lane (lr,lk) holds q-row lr,
// k-cols {w*256 + cf*16 + 4*lk + i}. Logits stay in registers; softmax via
// 2 shfl + tiny LDS cross-wave exchange; P stored bf16 (32KB, XOR-swizzled).
__global__ __launch_bounds__(256, 4)
void k_attn(const short* __restrict__ q, const short* __restrict__ kmat,
            const short* __restrict__ vT, const unsigned char* __restrict__ msk,
            float* __restrict__ attn, short* __restrict__ ctx) {
  __shared__ short P[16 * 1024];      // bf16 P, swizzled 16B slots
  __shared__ float redM[16][4];
  __shared__ float redS[16][4];
  const int t = threadIdx.x, l = t & 63, w = t >> 6;
  const int lr = l & 15, lk = l >> 4;
  const int rt = blockIdx.x, h = blockIdx.y, b = blockIdx.z;
  const int bh = b * 16 + h;
  const int r0 = rt * 16;
  const size_t kvbase = (size_t)bh << 16;  // bh * 1024 * 64
  const float NEG = -3.402823466e38f;

  // Q fragment (B-operand): col lr -> q row r0+lr, k-octet lk
  bfx8 aq0 = *(const bfx8*)&q[kvbase + ((size_t)(r0 + lr) << 6) + lk * 8];
  bfx8 aq1 = *(const bfx8*)&q[kvbase + ((size_t)(r0 + lr) << 6) + 32 + lk * 8];

  const unsigned char* mb = msk + b * 1024;
  const bool rowok = mb[r0 + lr] != 0;

  // ---- phase 1: logits in registers ----
  f32x4 sc[16];
  #pragma unroll
  for (int cf = 0; cf < 16; cf++) {
    int col0 = w * 256 + cf * 16;
    const short* kp = &kmat[kvbase + ((size_t)(col0 + lr) << 6) + lk * 8];
    bfx8 bk0 = *(const bfx8*)kp;
    bfx8 bk1 = *(const bfx8*)(kp + 32);
    f32x4 acc = {};
    acc = __builtin_amdgcn_mfma_f32_16x16x32_bf16(bk0, aq0, acc, 0, 0, 0);
    acc = __builtin_amdgcn_mfma_f32_16x16x32_bf16(bk1, aq1, acc, 0, 0, 0);
    sc[cf] = acc;
  }
  // mask + scale
  #pragma unroll
  for (int cf = 0; cf < 16; cf++) {
    int colb = w * 256 + cf * 16 + 4 * lk;
    unsigned cm = *(const unsigned*)&mb[colb];   // 4 mask bytes, aligned
    #pragma unroll
    for (int i = 0; i < 4; i++) {
      bool ok = rowok && (((cm >> (8 * i)) & 0xffu) != 0u);
      sc[cf][i] = ok ? sc[cf][i] * 0.03125f : NEG;
    }
  }

  // ---- phase 2: softmax (row = lr, owned by lanes {lr, lr+16, lr+32, lr+48} x 4 waves) ----
  float m = NEG;
  #pragma unroll
  for (int cf = 0; cf < 16; cf++)
    #pragma unroll
    for (int i = 0; i < 4; i++) m = fmaxf(m, sc[cf][i]);
  m = fmaxf(m, __shfl_xor(m, 16));
  m = fmaxf(m, __shfl_xor(m, 32));
  if (lk == 0) redM[lr][w] = m;
  __syncthreads();
  {
    float4 mr = *(const float4*)&redM[lr][0];
    m = fmaxf(fmaxf(mr.x, mr.y), fmaxf(mr.z, mr.w));
  }
  float s = 0.f;
  #pragma unroll
  for (int cf = 0; cf < 16; cf++)
    #pragma unroll
    for (int i = 0; i < 4; i++) {
      sc[cf][i] = __expf(sc[cf][i] - m);
      s += sc[cf][i];
    }
  s += __shfl_xor(s, 16);
  s += __shfl_xor(s, 32);
  if (lk == 0) redS[lr][w] = s;
  __syncthreads();
  float inv;
  {
    float4 sr = *(const float4*)&redS[lr][0];
    inv = 1.0f / (sr.x + sr.y + sr.z + sr.w);
  }

  // ---- write attn (float4) + P bf16 to LDS (b64, swizzled) ----
  float* arow = attn + ((size_t)bh * 1024 + r0 + lr) * 1024 + 4 * lk;
  #pragma unroll
  for (int cf = 0; cf < 16; cf++) {
    int col0 = w * 256 + cf * 16;
    float4 pv;
    pv.x = sc[cf][0] * inv; pv.y = sc[cf][1] * inv;
    pv.z = sc[cf][2] * inv; pv.w = sc[cf][3] * inv;
    *(float4*)&arow[col0] = pv;
    union { ushort u[4]; uint2 d; } pk;
    pk.u[0] = (ushort)f2bfbits(pv.x); pk.u[1] = (ushort)f2bfbits(pv.y);
    pk.u[2] = (ushort)f2bfbits(pv.z); pk.u[3] = (ushort)f2bfbits(pv.w);
    int colbyte = (col0 + 4 * lk) * 2;
    int addr = lr * 2048 + ((((colbyte >> 4) ^ (lr & 7)) << 4) | (colbyte & 15));
    *(uint2*)((char*)P + addr) = pk.d;
  }
  __syncthreads();

  // ---- phase 3: ctx = P @ V, wave w owns dims w*16..w*16+15, 2 acc chains ----
  const short* vrow = &vT[kvbase + ((size_t)(w * 16 + lr) << 10)];
  f32x4 o0 = {}, o1 = {};
  #pragma unroll 8
  for (int ks = 0; ks < 32; ks += 2) {
    int cb0 = ks * 64 + lk * 16;
    int cb1 = cb0 + 64;
    bfx8 pa0 = *(const bfx8*)((const char*)P + lr * 2048 + (((cb0 >> 4) ^ (lr & 7)) << 4));
    bfx8 pa1 = *(const bfx8*)((const char*)P + lr * 2048 + (((cb1 >> 4) ^ (lr & 7)) << 4));
    bfx8 bv0 = *(const bfx8*)&vrow[ks * 32 + lk * 8];
    bfx8 bv1 = *(const bfx8*)&vrow[(ks + 1) * 32 + lk * 8];
    o0 = __builtin_amdgcn_mfma_f32_16x16x32_bf16(pa0, bv0, o0, 0, 0, 0);
    o1 = __builtin_amdgcn_mfma_f32_16x16x32_bf16(pa1, bv1, o1, 0, 0, 0);
  }
  #pragma unroll
  for (int i = 0; i < 4; i++) {
    float oo = o0[i] + o1[i];
    ctx[(((size_t)b << 10) + r0 + 4 * lk + i) * 1024 + (h << 6) + (w << 4) + lr] =
        f2bfbits(oo);
  }
}

// ---------------- launch ----------------

extern "C" void kernel_launch(void* const* d_in, const int* in_sizes, int n_in,
                              void* d_out, int out_size, void* d_ws, size_t ws_size,
                              hipStream_t stream) {
  const float* x    = (const float*)d_in[0];
  const int*   mask = (const int*)d_in[1];
  const float* Wqkv = (const float*)d_in[2];
  const float* bqkv = (const float*)d_in[3];
  const float* Wout = (const float*)d_in[4];
  const float* bout = (const float*)d_in[5];
  float* out  = (float*)d_out;
  float* attn = out + (size_t)4 * 1024 * 1024;

  char* ws = (char*)d_ws;
  short* xb    = (short*)(ws);                  //  8 MB  x bf16 [4096][1024]
  short* wqkvT = (short*)(ws + 8388608);        //  6 MB  [3072][1024]
  short* woutT = (short*)(ws + 14680064);       //  2 MB  [1024][1024]
  short* qws   = (short*)(ws + 16777216);       //  8 MB  [64][1024][64]
  short* kws   = (short*)(ws + 25165824);       //  8 MB  [64][1024][64]
  short* vTws  = (short*)(ws + 33554432);       //  8 MB  [64][64][1024]
  short* ctx   = (short*)(ws + 41943040);       //  8 MB  [4096][1024]
  unsigned char* msk = (unsigned char*)(ws + 50331648);  // 4 KB

  k_cvt_x<<<4096, 256, 0, stream>>>(x, xb);
  k_transpose<<<dim3(96, 32), dim3(32, 8), 0, stream>>>(Wqkv, wqkvT, 1024, 3072);
  k_transpose<<<dim3(32, 32), dim3(32, 8), 0, stream>>>(Wout, woutT, 1024, 1024);
  k_mask<<<16, 256, 0, stream>>>(mask, msk);
  k_gemm<<<dim3(24, 32), 256, 0, stream>>>(xb, wqkvT, bqkv, 1024, 0,
                                           qws, kws, vTws, nullptr);
  k_attn<<<dim3(64, 16, 4), 256, 0, stream>>>(qws, kws, vTws, msk, attn, ctx);
  k_gemm<<<dim3(8, 32), 256, 0, stream>>>(ctx, woutT, bout, 1024, 1,
                                          nullptr, nullptr, nullptr, out);
}

// Round 3
// 219.615 us; speedup vs baseline: 1.2230x; 1.2230x over previous
//
#include <hip/hip_runtime.h>
#include <stdint.h>

#define DEV static __device__ __forceinline__

typedef __attribute__((ext_vector_type(8))) __bf16 bfx8;
typedef __attribute__((ext_vector_type(4))) float f32x4;

DEV short f2bfbits(float f) {
  union { float f; unsigned u; } v; v.f = f;
  unsigned r = v.u + 0x7fffu + ((v.u >> 16) & 1u);
  return (short)(r >> 16);
}

DEV void gload_lds16(const void* g, void* lds) {
  __builtin_amdgcn_global_load_lds(
      (const __attribute__((address_space(1))) void*)g,
      (__attribute__((address_space(3))) void*)lds, 16, 0, 0);
}

// ---------------- prep kernels ----------------

__global__ void k_cvt_x(const float* __restrict__ src, short* __restrict__ dst) {
  int i = blockIdx.x * 256 + threadIdx.x;            // 4 floats per thread
  float4 v = ((const float4*)src)[i];
  union { short s[4]; uint64_t u; } o;
  o.s[0] = f2bfbits(v.x); o.s[1] = f2bfbits(v.y);
  o.s[2] = f2bfbits(v.z); o.s[3] = f2bfbits(v.w);
  ((uint64_t*)dst)[i] = o.u;
}

// src [R][C] f32 -> dst [C][R] bf16
__global__ void k_transpose(const float* __restrict__ src, short* __restrict__ dst,
                            int R, int C) {
  __shared__ float tile[32][33];
  int c0 = blockIdx.x * 32, r0 = blockIdx.y * 32;
  int tx = threadIdx.x, ty = threadIdx.y;            // block (32,8)
  #pragma unroll
  for (int j = 0; j < 32; j += 8)
    tile[ty + j][tx] = src[(size_t)(r0 + ty + j) * C + c0 + tx];
  __syncthreads();
  #pragma unroll
  for (int j = 0; j < 32; j += 8)
    dst[(size_t)(c0 + ty + j) * R + r0 + tx] = f2bfbits(tile[tx][ty + j]);
}

// msk[b][n]: n==0 -> 1 else mask[b][n-1]
__global__ void k_mask(const int* __restrict__ mask, unsigned char* __restrict__ msk) {
  int i = blockIdx.x * 256 + threadIdx.x;            // [0, 4096)
  int b = i >> 10, n = i & 1023;
  msk[i] = (n == 0) ? (unsigned char)1 : (unsigned char)(mask[b * 1023 + n - 1] != 0);
}

// ---------------- GEMM: C = A[M][K] @ Bt[N][K]^T + bias ----------------
__global__ __launch_bounds__(256)
void k_gemm(const short* __restrict__ A, const short* __restrict__ Bt,
            const float* __restrict__ bias, int K, int mode,
            short* __restrict__ q, short* __restrict__ kk,
            short* __restrict__ vT, float* __restrict__ outF) {
  __shared__ short As[128 * 32];
  __shared__ short Bs[128 * 32];
  const int t = threadIdx.x;
  const int l = t & 63, w = t >> 6;
  const int lr = l & 15, lk = l >> 4;
  const int m0 = blockIdx.y * 128, n0 = blockIdx.x * 128;
  const int wr = (w >> 1) * 64, wc = (w & 1) * 64;
  f32x4 acc[4][4] = {};

  const int srow = t >> 2;
  const int sc8 = (t & 3) * 8;
  const size_t aoff1 = (size_t)(m0 + srow) * K + sc8;
  const size_t aoff2 = (size_t)(m0 + srow + 64) * K + sc8;
  const size_t boff1 = (size_t)(n0 + srow) * K + sc8;
  const size_t boff2 = (size_t)(n0 + srow + 64) * K + sc8;
  short* asd1 = As + (t & ~63) * 8;
  short* asd2 = As + (t & ~63) * 8 + 2048;
  short* bsd1 = Bs + (t & ~63) * 8;
  short* bsd2 = Bs + (t & ~63) * 8 + 2048;

  for (int k0 = 0; k0 < K; k0 += 32) {
    gload_lds16(A + aoff1 + k0, asd1);
    gload_lds16(A + aoff2 + k0, asd2);
    gload_lds16(Bt + boff1 + k0, bsd1);
    gload_lds16(Bt + boff2 + k0, bsd2);
    __syncthreads();
    bfx8 af[4], bf[4];
    #pragma unroll
    for (int m = 0; m < 4; m++)
      af[m] = *(const bfx8*)&As[(wr + m * 16 + lr) * 32 + lk * 8];
    #pragma unroll
    for (int n = 0; n < 4; n++)
      bf[n] = *(const bfx8*)&Bs[(wc + n * 16 + lr) * 32 + lk * 8];
    #pragma unroll
    for (int m = 0; m < 4; m++)
      #pragma unroll
      for (int n = 0; n < 4; n++)
        acc[m][n] = __builtin_amdgcn_mfma_f32_16x16x32_bf16(af[m], bf[n], acc[m][n], 0, 0, 0);
    __syncthreads();
  }

  if (mode == 0) {
    #pragma unroll
    for (int m = 0; m < 4; m++) {
      int grb = m0 + wr + m * 16 + 4 * lk;
      #pragma unroll
      for (int n = 0; n < 4; n++) {
        int gc = n0 + wc + n * 16 + lr;
        float bv = bias[gc];
        int which = gc >> 10, rem = gc & 1023;
        int hh = rem >> 6, dd = rem & 63;
        #pragma unroll
        for (int i = 0; i < 4; i++) {
          int gr = grb + i;
          int bb = gr >> 10, nn = gr & 1023;
          size_t bh = (size_t)(bb * 16 + hh);
          short val = f2bfbits(acc[m][n][i] + bv);
          if (which == 0)      q [(bh << 16) + ((size_t)nn << 6) + dd] = val;
          else if (which == 1) kk[(bh << 16) + ((size_t)nn << 6) + dd] = val;
          else                 vT[(bh << 16) + ((size_t)dd << 10) + nn] = val;
        }
      }
    }
  } else {
    #pragma unroll
    for (int m = 0; m < 4; m++) {
      #pragma unroll
      for (int n = 0; n < 4; n++) {
        int gc = n0 + wc + n * 16 + lr;
        float bv = bias[gc];
        #pragma unroll
        for (int i = 0; i < 4; i++) {
          int gr = m0 + wr + m * 16 + 4 * lk + i;
          outF[(size_t)gr * 1024 + gc] = acc[m][n][i] + bv;
        }
      }
    }
  }
}

// ---------------- fused attention v3 ----------------
// WG = (b,h) x 16 q-rows, 4 waves. All K/V global traffic staged through LDS
// with contiguous global_load_lds (pre-swizzled source, XOR 16B-slot swizzle
// on reads). Logits in registers (swapped QK^T); P bf16 in LDS; attn streamed
// out at the end as full-line 1KB/instr stores (bf16->f32 expand).
__global__ __launch_bounds__(256, 3)
void k_attn(const short* __restrict__ q, const short* __restrict__ kmat,
            const short* __restrict__ vT, const unsigned char* __restrict__ msk,
            float* __restrict__ attn, short* __restrict__ ctx) {
  __shared__ short tile[8192];        // 16KB K/V chunk staging
  __shared__ short P[16 * 1024];      // 32KB bf16 P, swizzled 16B slots
  __shared__ float redM[16][4];
  __shared__ float redS[16][4];
  const int t = threadIdx.x, l = t & 63, w = t >> 6;
  const int lr = l & 15, lk = l >> 4;
  const int rt = blockIdx.x, h = blockIdx.y, b = blockIdx.z;
  const int bh = b * 16 + h;
  const int r0 = rt * 16;
  const size_t kvbase = (size_t)bh << 16;  // bh * 1024 * 64
  const float NEG = -3.402823466e38f;

  // Q fragment (B-operand): col lr -> q row r0+lr, k-octet lk (one-time load)
  bfx8 aq0 = *(const bfx8*)&q[kvbase + ((size_t)(r0 + lr) << 6) + lk * 8];
  bfx8 aq1 = *(const bfx8*)&q[kvbase + ((size_t)(r0 + lr) << 6) + 32 + lk * 8];

  const unsigned char* mb = msk + b * 1024;
  const bool rowok = mb[r0 + lr] != 0;

  // ---- phase 1: logits in registers, K staged in 128-row chunks ----
  f32x4 sc[16];
  #pragma unroll
  for (int c = 0; c < 8; c++) {
    #pragma unroll
    for (int qq = 0; qq < 4; qq++) {
      int o = qq * 4096 + t * 16;          // linear LDS byte offset
      int row = o >> 7;                    // K tile row (128B rows, 8 slots)
      int slot = (o >> 4) & 7;
      int srcslot = slot ^ (row & 7);      // inverse-swizzled global source
      gload_lds16(kmat + kvbase + ((size_t)(c * 128 + row) << 6) + srcslot * 8,
                  (char*)tile + qq * 4096 + w * 1024);
    }
    __syncthreads();
    #pragma unroll
    for (int j = 0; j < 2; j++) {
      int rowt = w * 32 + j * 16 + lr;
      int sw = rowt & 7;
      bfx8 bk0 = *(const bfx8*)((char*)tile + rowt * 128 + ((lk ^ sw) << 4));
      bfx8 bk1 = *(const bfx8*)((char*)tile + rowt * 128 + (((lk + 4) ^ sw) << 4));
      f32x4 acc = {};
      acc = __builtin_amdgcn_mfma_f32_16x16x32_bf16(bk0, aq0, acc, 0, 0, 0);
      acc = __builtin_amdgcn_mfma_f32_16x16x32_bf16(bk1, aq1, acc, 0, 0, 0);
      sc[c * 2 + j] = acc;
    }
    __syncthreads();
  }

  // ---- mask + scale ----
  #pragma unroll
  for (int c = 0; c < 8; c++)
    #pragma unroll
    for (int j = 0; j < 2; j++) {
      int colb = c * 128 + w * 32 + j * 16 + 4 * lk;
      unsigned cm = *(const unsigned*)&mb[colb];
      #pragma unroll
      for (int i = 0; i < 4; i++) {
        bool ok = rowok && (((cm >> (8 * i)) & 0xffu) != 0u);
        sc[c * 2 + j][i] = ok ? sc[c * 2 + j][i] * 0.03125f : NEG;
      }
    }

  // ---- phase 2: softmax over k (row = lr) ----
  float m = NEG;
  #pragma unroll
  for (int f = 0; f < 16; f++)
    #pragma unroll
    for (int i = 0; i < 4; i++) m = fmaxf(m, sc[f][i]);
  m = fmaxf(m, __shfl_xor(m, 16));
  m = fmaxf(m, __shfl_xor(m, 32));
  if (lk == 0) redM[lr][w] = m;
  __syncthreads();
  {
    float4 mr = *(const float4*)&redM[lr][0];
    m = fmaxf(fmaxf(mr.x, mr.y), fmaxf(mr.z, mr.w));
  }
  float s = 0.f;
  #pragma unroll
  for (int f = 0; f < 16; f++)
    #pragma unroll
    for (int i = 0; i < 4; i++) { sc[f][i] = __expf(sc[f][i] - m); s += sc[f][i]; }
  s += __shfl_xor(s, 16);
  s += __shfl_xor(s, 32);
  if (lk == 0) redS[lr][w] = s;
  __syncthreads();
  float inv;
  {
    float4 sr = *(const float4*)&redS[lr][0];
    inv = 1.0f / (sr.x + sr.y + sr.z + sr.w);
  }

  // ---- P (bf16) -> LDS, swizzled ----
  #pragma unroll
  for (int c = 0; c < 8; c++)
    #pragma unroll
    for (int j = 0; j < 2; j++) {
      union { ushort u[4]; uint2 d; } pk;
      pk.u[0] = (ushort)f2bfbits(sc[c * 2 + j][0] * inv);
      pk.u[1] = (ushort)f2bfbits(sc[c * 2 + j][1] * inv);
      pk.u[2] = (ushort)f2bfbits(sc[c * 2 + j][2] * inv);
      pk.u[3] = (ushort)f2bfbits(sc[c * 2 + j][3] * inv);
      int slot_lin = c * 16 + w * 4 + j * 2 + (lk >> 1);
      int addr = lr * 2048 + (((slot_lin ^ (lr & 7))) << 4) + ((lk & 1) << 3);
      *(uint2*)((char*)P + addr) = pk.d;
    }
  __syncthreads();

  // ---- phase 3: ctx = P @ V, V staged in 128-col chunks ----
  const int vrow = w * 16 + lr;          // dim row owned by this lane
  f32x4 o0 = {}, o1 = {};
  #pragma unroll
  for (int c = 0; c < 8; c++) {
    #pragma unroll
    for (int qq = 0; qq < 4; qq++) {
      int o = qq * 4096 + t * 16;
      int row = o >> 8;                  // V tile row = dim (256B rows, 16 slots)
      int slot = (o >> 4) & 15;
      int srcslot = slot ^ (row & 7);
      gload_lds16(vT + kvbase + ((size_t)row << 10) + c * 128 + srcslot * 8,
                  (char*)tile + qq * 4096 + w * 1024);
    }
    __syncthreads();
    #pragma unroll
    for (int ks = 0; ks < 4; ks++) {
      int ksg = c * 4 + ks;
      int pslot = ksg * 4 + lk;
      bfx8 pa = *(const bfx8*)((const char*)P + lr * 2048 + ((pslot ^ (lr & 7)) << 4));
      int vslot = ks * 4 + lk;
      bfx8 bv = *(const bfx8*)((const char*)tile + vrow * 256 + ((vslot ^ (lr & 7)) << 4));
      if (ks & 1) o1 = __builtin_amdgcn_mfma_f32_16x16x32_bf16(pa, bv, o1, 0, 0, 0);
      else        o0 = __builtin_amdgcn_mfma_f32_16x16x32_bf16(pa, bv, o0, 0, 0, 0);
    }
    __syncthreads();
  }
  #pragma unroll
  for (int i = 0; i < 4; i++) {
    float oo = o0[i] + o1[i];
    ctx[(((size_t)b << 10) + r0 + 4 * lk + i) * 1024 + (h << 6) + (w << 4) + lr] =
        f2bfbits(oo);
  }

  // ---- stream attn out from P: full-line contiguous stores ----
  #pragma unroll
  for (int rg = 0; rg < 4; rg++) {
    int row = w * 4 + rg;
    float* arow = attn + ((size_t)bh * 1024 + r0 + row) * 1024;
    int sw = row & 7;
    #pragma unroll
    for (int it = 0; it < 4; it++) {
      int ci = it * 64 + l;              // 16B output chunk index (4 f32)
      int slot_lin = ci >> 1, half = ci & 1;
      uint2 d = *(const uint2*)((const char*)P + row * 2048 +
                                ((slot_lin ^ sw) << 4) + (half << 3));
      float4 o;
      o.x = __uint_as_float(d.x << 16);
      o.y = __uint_as_float(d.x & 0xffff0000u);
      o.z = __uint_as_float(d.y << 16);
      o.w = __uint_as_float(d.y & 0xffff0000u);
      *(float4*)&arow[ci * 4] = o;
    }
  }
}

// ---------------- launch ----------------

extern "C" void kernel_launch(void* const* d_in, const int* in_sizes, int n_in,
                              void* d_out, int out_size, void* d_ws, size_t ws_size,
                              hipStream_t stream) {
  const float* x    = (const float*)d_in[0];
  const int*   mask = (const int*)d_in[1];
  const float* Wqkv = (const float*)d_in[2];
  const float* bqkv = (const float*)d_in[3];
  const float* Wout = (const float*)d_in[4];
  const float* bout = (const float*)d_in[5];
  float* out  = (float*)d_out;
  float* attn = out + (size_t)4 * 1024 * 1024;

  char* ws = (char*)d_ws;
  short* xb    = (short*)(ws);                  //  8 MB  x bf16 [4096][1024]
  short* wqkvT = (short*)(ws + 8388608);        //  6 MB  [3072][1024]
  short* woutT = (short*)(ws + 14680064);       //  2 MB  [1024][1024]
  short* qws   = (short*)(ws + 16777216);       //  8 MB  [64][1024][64]
  short* kws   = (short*)(ws + 25165824);       //  8 MB  [64][1024][64]
  short* vTws  = (short*)(ws + 33554432);       //  8 MB  [64][64][1024]
  short* ctx   = (short*)(ws + 41943040);       //  8 MB  [4096][1024]
  unsigned char* msk = (unsigned char*)(ws + 50331648);  // 4 KB

  k_cvt_x<<<4096, 256, 0, stream>>>(x, xb);
  k_transpose<<<dim3(96, 32), dim3(32, 8), 0, stream>>>(Wqkv, wqkvT, 1024, 3072);
  k_transpose<<<dim3(32, 32), dim3(32, 8), 0, stream>>>(Wout, woutT, 1024, 1024);
  k_mask<<<16, 256, 0, stream>>>(mask, msk);
  k_gemm<<<dim3(24, 32), 256, 0, stream>>>(xb, wqkvT, bqkv, 1024, 0,
                                           qws, kws, vTws, nullptr);
  k_attn<<<dim3(64, 16, 4), 256, 0, stream>>>(qws, kws, vTws, msk, attn, ctx);
  k_gemm<<<dim3(8, 32), 256, 0, stream>>>(ctx, woutT, bout, 1024, 1,
                                          nullptr, nullptr, nullptr, out);
}